// Round 1
// baseline (435.391 us; speedup 1.0000x reference)
//
#include <hip/hip_runtime.h>
#include <math.h>

#define NT 256      // threads per block
#define NS 4096     // 2^12 amplitudes

struct M2 { float2 m00, m01, m10, m11; };

// a0' = u00*a0 + u01*a1 ; a1' = u10*a0 + u11*a1   (complex)
__device__ __forceinline__ void app1(const M2& u, float2& a0, float2& a1) {
    float2 n0, n1;
    n0.x = u.m00.x*a0.x - u.m00.y*a0.y + u.m01.x*a1.x - u.m01.y*a1.y;
    n0.y = u.m00.x*a0.y + u.m00.y*a0.x + u.m01.x*a1.y + u.m01.y*a1.x;
    n1.x = u.m10.x*a0.x - u.m10.y*a0.y + u.m11.x*a1.x - u.m11.y*a1.y;
    n1.y = u.m10.x*a0.y + u.m10.y*a0.x + u.m11.x*a1.y + u.m11.y*a1.x;
    a0 = n0; a1 = n1;
}

// Apply two single-qubit gates (uH on bit bHi, uL on bit bLo) in one LDS pass.
__device__ __forceinline__ void gate2_pass(float2* psi, int t, int bHi, int bLo,
                                           M2 uH, M2 uL) {
    const int sLo = 1 << bLo, sHi = 1 << bHi;
    const int mLo = sLo - 1;
    const int mMid = (1 << (bHi - bLo - 1)) - 1;
    #pragma unroll
    for (int pp = 0; pp < 4; ++pp) {
        int g = t + pp * NT;                   // 1024 groups of 4 amplitudes
        int lo  = g & mLo;
        int mid = (g >> bLo) & mMid;
        int hi  = g >> (bHi - 1);
        int base = (hi << (bHi + 1)) | (mid << (bLo + 1)) | lo;
        float2 v00 = psi[base];
        float2 v01 = psi[base + sLo];
        float2 v10 = psi[base + sHi];
        float2 v11 = psi[base + sLo + sHi];
        app1(uH, v00, v10);   // gate on high bit mixes (x0x <-> x1x)
        app1(uH, v01, v11);
        app1(uL, v00, v01);   // gate on low bit
        app1(uL, v10, v11);
        psi[base]             = v00;
        psi[base + sLo]       = v01;
        psi[base + sHi]       = v10;
        psi[base + sLo + sHi] = v11;
    }
    __syncthreads();
}

// CNOT ring:  gates CNOT(i,(i+1)%12), i=0..11.  Wire j <-> bit (11-j).
// Forward basis-permutation pi(k)  (wire-space prefix XOR, then w0 ^= p11):
__device__ __forceinline__ int ring_pi(int k) {
    int u = k ^ (k >> 1);
    u ^= u >> 2; u ^= u >> 4; u ^= u >> 8;     // bit b = XOR of bits >= b
    int w0 = ((u >> 11) ^ u) & 1;              // w0' = w0 ^ p11
    return (u & 0x7FF) | (w0 << 11);
}
// Inverse permutation sigma = pi^{-1}  (read-index for psi_new[k] = psi_old[sigma(k)])
__device__ __forceinline__ int ring_sigma(int k) {
    int s = (k ^ (k >> 1)) & 0x3FF;            // wires 2..11: w_j ^= w_{j-1}
    int b10 = ((k >> 10) ^ (k >> 11) ^ k) & 1; // w1' = w1 ^ w0 ^ w11
    int b11 = ((k >> 11) ^ k) & 1;             // w0' = w0 ^ w11
    return s | (b10 << 10) | (b11 << 11);
}

__device__ __forceinline__ void perm_pass(float2* psi, int t) {
    float2 r[16];
    #pragma unroll
    for (int j = 0; j < 16; ++j)
        r[j] = psi[ring_sigma(t + j * NT)];
    __syncthreads();
    #pragma unroll
    for (int j = 0; j < 16; ++j)
        psi[t + j * NT] = r[j];
    __syncthreads();
}

__global__ __launch_bounds__(NT, 4)
void tqhea_kernel(const float* __restrict__ x,     // (B, 24)
                  const float* __restrict__ wts,   // (6, 3, 12)
                  float* __restrict__ out)         // (B, 1)
{
    __shared__ float2 psi[NS];       // 32 KB
    __shared__ M2     U[72];         // 6 ansatz blocks x 12 wires, fused RY*RZ*RY
    __shared__ float2 rxcs[24];      // (cos, sin) of each RX half-angle
    __shared__ float  redbuf[4];

    const int b = blockIdx.x;
    const int t = threadIdx.x;

    // ---- precompute fused ansatz unitaries U = RY(t2) * RZ(t1) * RY(t0)
    if (t < 72) {
        int ab = t / 12, w = t % 12;
        float a  = 0.5f * wts[(ab * 3 + 0) * 12 + w];   // first RY
        float bb = 0.5f * wts[(ab * 3 + 1) * 12 + w];   // RZ
        float g  = 0.5f * wts[(ab * 3 + 2) * 12 + w];   // last RY
        float sa, ca, sb, cb, sg, cg;
        sincosf(a,  &sa, &ca);
        sincosf(bb, &sb, &cb);
        sincosf(g,  &sg, &cg);
        float C1 = ca * cg - sa * sg;   // cos(a+g)
        float S1 = sa * cg + ca * sg;   // sin(a+g)
        float C2 = ca * cg + sa * sg;   // cos(a-g)
        float S2 = sa * cg - ca * sg;   // sin(a-g)
        M2 u;
        u.m00 = make_float2( cb * C1, -sb * C2);
        u.m01 = make_float2(-cb * S1,  sb * S2);
        u.m10 = make_float2( cb * S1,  sb * S2);
        u.m11 = make_float2( cb * C1,  sb * C2);
        U[t] = u;
    }
    if (t < 24) {
        float th = 0.5f * x[b * 24 + t];
        rxcs[t] = make_float2(cosf(th), sinf(th));
    }
    __syncthreads();

    // ---- init = |0..0> with first RX layer applied (product state), one write pass
    {
        float2 cs[12];
        #pragma unroll
        for (int wq = 0; wq < 12; ++wq) cs[wq] = rxcs[wq];
        #pragma unroll
        for (int j = 0; j < 16; ++j) {
            int k = t + j * NT;
            float mag = 1.f;
            #pragma unroll
            for (int wq = 0; wq < 12; ++wq)
                mag *= ((k >> (11 - wq)) & 1) ? cs[wq].y : cs[wq].x;
            int pc = __popc(k) & 3;      // phase (-i)^popcount
            float2 v;
            v.x = (pc == 0) ? mag : ((pc == 2) ? -mag : 0.f);
            v.y = (pc == 1) ? -mag : ((pc == 3) ? mag : 0.f);
            psi[k] = v;
        }
    }
    __syncthreads();

    // ---- block 0: 3 ansatz layers (U-layer as 6 fused 2q passes, then CNOT ring)
    for (int l = 0; l < 3; ++l) {
        #pragma unroll
        for (int w = 0; w < 6; ++w)
            gate2_pass(psi, t, 11 - w, 5 - w, U[l * 12 + w], U[l * 12 + w + 6]);
        perm_pass(psi, t);
    }

    // ---- block 1 encode: second RX layer, pairwise fused
    #pragma unroll
    for (int w = 0; w < 6; ++w) {
        float2 csH = rxcs[12 + w], csL = rxcs[12 + w + 6];
        M2 uH, uL;
        uH.m00 = make_float2(csH.x, 0.f); uH.m01 = make_float2(0.f, -csH.y);
        uH.m10 = make_float2(0.f, -csH.y); uH.m11 = make_float2(csH.x, 0.f);
        uL.m00 = make_float2(csL.x, 0.f); uL.m01 = make_float2(0.f, -csL.y);
        uL.m10 = make_float2(0.f, -csL.y); uL.m11 = make_float2(csL.x, 0.f);
        gate2_pass(psi, t, 11 - w, 5 - w, uH, uL);
    }

    // ---- block 1: 3 ansatz layers; final CNOT ring folded into the reduction
    for (int l = 0; l < 3; ++l) {
        #pragma unroll
        for (int w = 0; w < 6; ++w)
            gate2_pass(psi, t, 11 - w, 5 - w, U[(3 + l) * 12 + w], U[(3 + l) * 12 + w + 6]);
        if (l < 2) perm_pass(psi, t);
    }

    // ---- <H> = sum_k |psi[pi^{-1}(k)]|^2 * (12 - 2*popcount(k))
    //        == sum_j |psi[j]|^2 * (12 - 2*popcount(pi(j)))
    float acc = 0.f;
    #pragma unroll
    for (int j = 0; j < 16; ++j) {
        int k = t + j * NT;
        float2 v = psi[k];
        float d = 12.0f - 2.0f * (float)__popc(ring_pi(k));
        acc += (v.x * v.x + v.y * v.y) * d;
    }
    #pragma unroll
    for (int off = 32; off > 0; off >>= 1)
        acc += __shfl_down(acc, off);
    int wid = t >> 6, lane = t & 63;
    if (lane == 0) redbuf[wid] = acc;
    __syncthreads();
    if (t == 0) out[b] = redbuf[0] + redbuf[1] + redbuf[2] + redbuf[3];
}

extern "C" void kernel_launch(void* const* d_in, const int* in_sizes, int n_in,
                              void* d_out, int out_size, void* d_ws, size_t ws_size,
                              hipStream_t stream) {
    const float* x   = (const float*)d_in[0];   // (B, 24) float32
    const float* wts = (const float*)d_in[1];   // (6, 3, 12) float32
    float* out = (float*)d_out;                 // (B, 1) float32
    int B = in_sizes[0] / 24;
    tqhea_kernel<<<dim3(B), dim3(NT), 0, stream>>>(x, wts, out);
}

// Round 2
// 402.430 us; speedup vs baseline: 1.0819x; 1.0819x over previous
//
#include <hip/hip_runtime.h>
#include <math.h>

#define NT 256      // threads per block
#define NS 4096     // 2^12 amplitudes

// ---- storage swizzle: XOR bits 7..4 into bits 3..0 (bank-conflict-free for all 3 mappings)
__device__ __forceinline__ int swz(int k) { return k ^ ((k >> 4) & 0xF); }

// CNOT ring: gates CNOT(i,(i+1)%12), wire j <-> bit (11-j).
// forward basis permutation pi(k):
__device__ __forceinline__ int ring_pi(int k) {
    int u = k ^ (k >> 1);
    u ^= u >> 2; u ^= u >> 4; u ^= u >> 8;
    int w0 = ((u >> 11) ^ u) & 1;
    return (u & 0x7FF) | (w0 << 11);
}
// inverse permutation: psi_new[k] = psi_old[ring_sigma(k)]
__device__ __forceinline__ int ring_sigma(int k) {
    int s = (k ^ (k >> 1)) & 0x3FF;
    int b10 = ((k >> 10) ^ (k >> 11) ^ k) & 1;
    int b11 = ((k >> 11) ^ k) & 1;
    return s | (b10 << 10) | (b11 << 11);
}

// Gate in ABCD form: G = [[A-iB, -C+iD],[C+iD, A+iB]]  (RY*RZ*RY and RX both fit)
__device__ __forceinline__ void app1(float A, float B, float C, float D,
                                     float2& a0, float2& a1) {
    float2 n0, n1;
    n0.x = A*a0.x + B*a0.y - C*a1.x - D*a1.y;
    n0.y = A*a0.y - B*a0.x - C*a1.y + D*a1.x;
    n1.x = C*a0.x - D*a0.y + A*a1.x - B*a1.y;
    n1.y = C*a0.y + D*a0.x + A*a1.y + B*a1.x;
    a0 = n0; a1 = n1;
}

template<int P>
__device__ __forceinline__ void gate_on_bit(float2 a[16], float4 g) {
    #pragma unroll
    for (int r = 0; r < 16; ++r) {
        if (r & (1 << P)) continue;
        app1(g.x, g.y, g.z, g.w, a[r], a[r | (1 << P)]);
    }
}

__global__ __launch_bounds__(NT, 4)
void tqhea_kernel(const float* __restrict__ x,     // (B, 24)
                  const float* __restrict__ wts,   // (6, 3, 12)
                  float* __restrict__ out)         // (B, 1)
{
    __shared__ float2 psi[NS];       // 32 KB, swizzled storage
    __shared__ float4 U[72];         // fused gates in ABCD form
    __shared__ float2 rxcs[12];      // (cos,sin) of first RX layer half-angles
    __shared__ float  redbuf[4];

    const int b = blockIdx.x;
    const int t = threadIdx.x;

    // ---- precompute fused U = RY(g)*RZ(b)*RY(a); block 3 also folds RX (mid encode layer)
    if (t < 72) {
        int ab = t / 12, w = t % 12;
        float a  = 0.5f * wts[(ab * 3 + 0) * 12 + w];
        float bb = 0.5f * wts[(ab * 3 + 1) * 12 + w];
        float g  = 0.5f * wts[(ab * 3 + 2) * 12 + w];
        float sa, ca, sb, cb, sg, cg;
        sincosf(a,  &sa, &ca);
        sincosf(bb, &sb, &cb);
        sincosf(g,  &sg, &cg);
        float A = cb * (ca * cg - sa * sg);   // cb*cos(a+g)
        float B = sb * (ca * cg + sa * sg);   // sb*cos(a-g)
        float C = cb * (sa * cg + ca * sg);   // cb*sin(a+g)
        float D = sb * (sa * cg - ca * sg);   // sb*sin(a-g)
        if (ab == 3) {                        // U' = U * RX(x[12+w]); ABCD closed form
            float th = 0.5f * x[b * 24 + 12 + w];
            float s, c; sincosf(th, &s, &c);
            float A2 = A*c + D*s, B2 = B*c - C*s, C2 = C*c + B*s, D2 = D*c - A*s;
            A = A2; B = B2; C = C2; D = D2;
        }
        U[t] = make_float4(A, B, C, D);
    }
    if (t < 12) {
        float th = 0.5f * x[b * 24 + t];
        float s, c; sincosf(th, &s, &c);
        rxcs[t] = make_float2(c, s);
    }
    __syncthreads();

    const int tsw = t ^ ((t >> 4) & 0xF);          // P0 swizzled low byte

    // ---- init: |0..0> + first RX layer = product state, write-only pass (P0 ownership)
    {
        float mlo = 1.f;
        #pragma unroll
        for (int bit = 0; bit < 8; ++bit)          // k bit 'bit' <-> wire 11-bit
            mlo *= ((t >> bit) & 1) ? rxcs[11 - bit].y : rxcs[11 - bit].x;
        int pct = __popc(t);
        #pragma unroll
        for (int r = 0; r < 16; ++r) {
            float mhi = 1.f;
            #pragma unroll
            for (int p = 0; p < 4; ++p)            // r bit p <-> wire 3-p
                mhi *= ((r >> p) & 1) ? rxcs[3 - p].y : rxcs[3 - p].x;
            float mag = mhi * mlo;
            int pc = (pct + __popc(r)) & 3;        // (-i)^popcount phase
            float2 v;
            v.x = (pc == 0) ? mag : ((pc == 2) ? -mag : 0.f);
            v.y = (pc == 1) ? -mag : ((pc == 3) ? mag : 0.f);
            psi[(r << 8) | tsw] = v;
        }
    }
    __syncthreads();

    // ---- 6 ansatz layers; CNOT ring after layer l folded into layer l+1's P0 read
    #pragma unroll 1
    for (int l = 0; l < 6; ++l) {
        float2 a[16];
        // P0: wires 0..3 (k bits 11..8 register-local)
        if (l == 0) {
            #pragma unroll
            for (int r = 0; r < 16; ++r) a[r] = psi[(r << 8) | tsw];
        } else {
            #pragma unroll
            for (int r = 0; r < 16; ++r)
                a[r] = psi[swz(ring_sigma((r << 8) | t))];   // ring from layer l-1
            __syncthreads();                                  // gather-read: all reads before writes
        }
        gate_on_bit<3>(a, U[l * 12 + 0]);
        gate_on_bit<2>(a, U[l * 12 + 1]);
        gate_on_bit<1>(a, U[l * 12 + 2]);
        gate_on_bit<0>(a, U[l * 12 + 3]);
        #pragma unroll
        for (int r = 0; r < 16; ++r) psi[(r << 8) | tsw] = a[r];
        __syncthreads();

        // P1: wires 4..7 (k bits 7..4 register-local); addr = base1 ^ 17r
        const int base1 = ((t & 0xF0) << 4) | (t & 0xF);
        #pragma unroll
        for (int r = 0; r < 16; ++r) a[r] = psi[base1 ^ (17 * r)];
        gate_on_bit<3>(a, U[l * 12 + 4]);
        gate_on_bit<2>(a, U[l * 12 + 5]);
        gate_on_bit<1>(a, U[l * 12 + 6]);
        gate_on_bit<0>(a, U[l * 12 + 7]);
        #pragma unroll
        for (int r = 0; r < 16; ++r) psi[base1 ^ (17 * r)] = a[r];
        __syncthreads();

        // P2: wires 8..11 (k bits 3..0 register-local); addr = base2 ^ r
        const int base2 = (t << 4) | (t & 0xF);
        #pragma unroll
        for (int r = 0; r < 16; ++r) a[r] = psi[base2 ^ r];
        gate_on_bit<3>(a, U[l * 12 + 8]);
        gate_on_bit<2>(a, U[l * 12 + 9]);
        gate_on_bit<1>(a, U[l * 12 + 10]);
        gate_on_bit<0>(a, U[l * 12 + 11]);
        #pragma unroll
        for (int r = 0; r < 16; ++r) psi[base2 ^ r] = a[r];
        __syncthreads();
    }

    // ---- <H>: final ring folded in via pi; diag = 12 - 2*popc
    float acc = 0.f;
    #pragma unroll
    for (int r = 0; r < 16; ++r) {
        int k = (r << 8) | t;
        float2 v = psi[(r << 8) | tsw];
        float d = 12.0f - 2.0f * (float)__popc(ring_pi(k));
        acc += (v.x * v.x + v.y * v.y) * d;
    }
    #pragma unroll
    for (int off = 32; off > 0; off >>= 1)
        acc += __shfl_down(acc, off);
    int wid = t >> 6, lane = t & 63;
    if (lane == 0) redbuf[wid] = acc;
    __syncthreads();
    if (t == 0) out[b] = redbuf[0] + redbuf[1] + redbuf[2] + redbuf[3];
}

extern "C" void kernel_launch(void* const* d_in, const int* in_sizes, int n_in,
                              void* d_out, int out_size, void* d_ws, size_t ws_size,
                              hipStream_t stream) {
    const float* x   = (const float*)d_in[0];   // (B, 24) float32
    const float* wts = (const float*)d_in[1];   // (6, 3, 12) float32
    float* out = (float*)d_out;                 // (B, 1) float32
    int B = in_sizes[0] / 24;
    tqhea_kernel<<<dim3(B), dim3(NT), 0, stream>>>(x, wts, out);
}

// Round 3
// 365.925 us; speedup vs baseline: 1.1898x; 1.0998x over previous
//
#include <hip/hip_runtime.h>
#include <math.h>

#define NT 256      // threads per block
#define NS 4096     // 2^12 amplitudes

// ---- storage swizzle: XOR bits 7..4 into bits 3..0 (bank-conflict-free for all 3 mappings)
__device__ __forceinline__ int swz(int k) { return k ^ ((k >> 4) & 0xF); }

// CNOT ring: gates CNOT(i,(i+1)%12), wire j <-> bit (11-j).
// forward basis permutation pi(k):
__device__ __forceinline__ int ring_pi(int k) {
    int u = k ^ (k >> 1);
    u ^= u >> 2; u ^= u >> 4; u ^= u >> 8;
    int w0 = ((u >> 11) ^ u) & 1;
    return (u & 0x7FF) | (w0 << 11);
}
// inverse permutation: psi_new[k] = psi_old[ring_sigma(k)]
__device__ __forceinline__ int ring_sigma(int k) {
    int s = (k ^ (k >> 1)) & 0x3FF;
    int b10 = ((k >> 10) ^ (k >> 11) ^ k) & 1;
    int b11 = ((k >> 11) ^ k) & 1;
    return s | (b10 << 10) | (b11 << 11);
}

// Gate in ABCD form: G = [[A-iB, -C+iD],[C+iD, A+iB]]  (RY*RZ*RY and RX both fit)
__device__ __forceinline__ void app1(float A, float B, float C, float D,
                                     float2& a0, float2& a1) {
    float2 n0, n1;
    n0.x = A*a0.x + B*a0.y - C*a1.x - D*a1.y;
    n0.y = A*a0.y - B*a0.x - C*a1.y + D*a1.x;
    n1.x = C*a0.x - D*a0.y + A*a1.x - B*a1.y;
    n1.y = C*a0.y + D*a0.x + A*a1.y + B*a1.x;
    a0 = n0; a1 = n1;
}

template<int P>
__device__ __forceinline__ void gate_on_bit(float2 a[16], float4 g) {
    #pragma unroll
    for (int r = 0; r < 16; ++r) {
        if (r & (1 << P)) continue;
        app1(g.x, g.y, g.z, g.w, a[r], a[r | (1 << P)]);
    }
}

__global__ __launch_bounds__(NT, 2)   // 2 waves/EU min -> VGPR budget 256, no spill
void tqhea_kernel(const float* __restrict__ x,     // (B, 24)
                  const float* __restrict__ wts,   // (6, 3, 12)
                  float* __restrict__ out)         // (B, 1)
{
    __shared__ float2 psi[NS];       // 32 KB, swizzled storage
    __shared__ float4 U[72];         // fused gates in ABCD form
    __shared__ float2 rxcs[12];      // (cos,sin) of first RX layer half-angles
    __shared__ float  redbuf[4];

    const int b = blockIdx.x;
    const int t = threadIdx.x;

    // ---- precompute fused U = RY(g)*RZ(b)*RY(a); block 3 also folds RX (mid encode layer)
    if (t < 72) {
        int ab = t / 12, w = t % 12;
        float a  = 0.5f * wts[(ab * 3 + 0) * 12 + w];
        float bb = 0.5f * wts[(ab * 3 + 1) * 12 + w];
        float g  = 0.5f * wts[(ab * 3 + 2) * 12 + w];
        float sa, ca, sb, cb, sg, cg;
        sincosf(a,  &sa, &ca);
        sincosf(bb, &sb, &cb);
        sincosf(g,  &sg, &cg);
        float A = cb * (ca * cg - sa * sg);   // cb*cos(a+g)
        float B = sb * (ca * cg + sa * sg);   // sb*cos(a-g)
        float C = cb * (sa * cg + ca * sg);   // cb*sin(a+g)
        float D = sb * (sa * cg - ca * sg);   // sb*sin(a-g)
        if (ab == 3) {                        // U' = U * RX(x[12+w]); ABCD closed form
            float th = 0.5f * x[b * 24 + 12 + w];
            float s, c; sincosf(th, &s, &c);
            float A2 = A*c + D*s, B2 = B*c - C*s, C2 = C*c + B*s, D2 = D*c - A*s;
            A = A2; B = B2; C = C2; D = D2;
        }
        U[t] = make_float4(A, B, C, D);
    }
    if (t < 12) {
        float th = 0.5f * x[b * 24 + t];
        float s, c; sincosf(th, &s, &c);
        rxcs[t] = make_float2(c, s);
    }
    __syncthreads();

    const int tsw = t ^ ((t >> 4) & 0xF);          // P0 swizzled low byte

    // ---- init: |0..0> + first RX layer = product state, write-only pass (P0 ownership)
    {
        float mlo = 1.f;
        #pragma unroll
        for (int bit = 0; bit < 8; ++bit)          // k bit 'bit' <-> wire 11-bit
            mlo *= ((t >> bit) & 1) ? rxcs[11 - bit].y : rxcs[11 - bit].x;
        int pct = __popc(t);
        #pragma unroll
        for (int r = 0; r < 16; ++r) {
            float mhi = 1.f;
            #pragma unroll
            for (int p = 0; p < 4; ++p)            // r bit p <-> wire 3-p
                mhi *= ((r >> p) & 1) ? rxcs[3 - p].y : rxcs[3 - p].x;
            float mag = mhi * mlo;
            int pc = (pct + __popc(r)) & 3;        // (-i)^popcount phase
            float2 v;
            v.x = (pc == 0) ? mag : ((pc == 2) ? -mag : 0.f);
            v.y = (pc == 1) ? -mag : ((pc == 3) ? mag : 0.f);
            psi[(r << 8) | tsw] = v;
        }
    }
    __syncthreads();

    float acc = 0.f;

    // ---- 6 ansatz layers; CNOT ring after layer l folded into layer l+1's P0 read;
    //      last layer's P2 pass folds straight into the reduction (no final sweep)
    #pragma unroll 1
    for (int l = 0; l < 6; ++l) {
        float2 a[16];
        // P0: wires 0..3 (k bits 11..8 register-local)
        if (l == 0) {
            #pragma unroll
            for (int r = 0; r < 16; ++r) a[r] = psi[(r << 8) | tsw];
        } else {
            #pragma unroll
            for (int r = 0; r < 16; ++r)
                a[r] = psi[swz(ring_sigma((r << 8) | t))];   // ring from layer l-1
            __syncthreads();                                  // all reads before any writes
        }
        gate_on_bit<3>(a, U[l * 12 + 0]);
        gate_on_bit<2>(a, U[l * 12 + 1]);
        gate_on_bit<1>(a, U[l * 12 + 2]);
        gate_on_bit<0>(a, U[l * 12 + 3]);
        #pragma unroll
        for (int r = 0; r < 16; ++r) psi[(r << 8) | tsw] = a[r];
        __syncthreads();

        // P1: wires 4..7 (k bits 7..4 register-local); addr = base1 ^ 17r
        const int base1 = ((t & 0xF0) << 4) | (t & 0xF);
        #pragma unroll
        for (int r = 0; r < 16; ++r) a[r] = psi[base1 ^ (17 * r)];
        gate_on_bit<3>(a, U[l * 12 + 4]);
        gate_on_bit<2>(a, U[l * 12 + 5]);
        gate_on_bit<1>(a, U[l * 12 + 6]);
        gate_on_bit<0>(a, U[l * 12 + 7]);
        #pragma unroll
        for (int r = 0; r < 16; ++r) psi[base1 ^ (17 * r)] = a[r];
        __syncthreads();

        // P2: wires 8..11 (k bits 3..0 register-local); addr = base2 ^ r
        const int base2 = (t << 4) | (t & 0xF);
        #pragma unroll
        for (int r = 0; r < 16; ++r) a[r] = psi[base2 ^ r];
        gate_on_bit<3>(a, U[l * 12 + 8]);
        gate_on_bit<2>(a, U[l * 12 + 9]);
        gate_on_bit<1>(a, U[l * 12 + 10]);
        gate_on_bit<0>(a, U[l * 12 + 11]);
        if (l < 5) {
            #pragma unroll
            for (int r = 0; r < 16; ++r) psi[base2 ^ r] = a[r];
            __syncthreads();
        } else {
            // ---- <H>: final ring folded via pi; thread t, reg r hold k=(t<<4)|r
            #pragma unroll
            for (int r = 0; r < 16; ++r) {
                int k = (t << 4) | r;
                float d = 12.0f - 2.0f * (float)__popc(ring_pi(k));
                acc += (a[r].x * a[r].x + a[r].y * a[r].y) * d;
            }
        }
    }

    #pragma unroll
    for (int off = 32; off > 0; off >>= 1)
        acc += __shfl_down(acc, off);
    int wid = t >> 6, lane = t & 63;
    if (lane == 0) redbuf[wid] = acc;
    __syncthreads();
    if (t == 0) out[b] = redbuf[0] + redbuf[1] + redbuf[2] + redbuf[3];
}

extern "C" void kernel_launch(void* const* d_in, const int* in_sizes, int n_in,
                              void* d_out, int out_size, void* d_ws, size_t ws_size,
                              hipStream_t stream) {
    const float* x   = (const float*)d_in[0];   // (B, 24) float32
    const float* wts = (const float*)d_in[1];   // (6, 3, 12) float32
    float* out = (float*)d_out;                 // (B, 1) float32
    int B = in_sizes[0] / 24;
    tqhea_kernel<<<dim3(B), dim3(NT), 0, stream>>>(x, wts, out);
}

// Round 4
// 211.068 us; speedup vs baseline: 2.0628x; 1.7337x over previous
//
#include <hip/hip_runtime.h>
#include <math.h>

#define NT 256      // threads per block
#define NS 4096     // 2^12 amplitudes

typedef float f32x2 __attribute__((ext_vector_type(2)));

// CNOT ring: gates CNOT(i,(i+1)%12), wire j <-> bit (11-j).
// forward basis permutation pi(k), GF(2)-linear:
constexpr int ring_pi_c(int k) {
    int u = k ^ (k >> 1);
    u ^= u >> 2; u ^= u >> 4; u ^= u >> 8;
    int w0 = ((u >> 11) ^ u) & 1;
    return (u & 0x7FF) | (w0 << 11);
}
// storage swizzle (GF(2)-linear): rank-4 bank map for P0/P1/P2 reads+writes
constexpr int sig2(int m) { return m ^ ((m >> 4) & 0xF) ^ ((m >> 8) & 0xF); }

// Fused gate G = [[A-iB, -C+iD],[C+iD, A+iB]] applied to (a0,a1), packed fp32.
// ab=(A,B), cd=(C,D). 8 VOP3P inst = 16 scalar-FMA equivalents.
__device__ __forceinline__ void app1p(f32x2 ab, f32x2 cd, f32x2& a0, f32x2& a1) {
    f32x2 n0, n1;
    asm("v_pk_mul_f32 %0, %2, %4 op_sel:[0,0] op_sel_hi:[1,0]\n\t"
        "v_pk_fma_f32 %0, %2, %4, %0 op_sel:[1,1,0] op_sel_hi:[0,1,1] neg_hi:[0,1,0]\n\t"
        "v_pk_fma_f32 %0, %3, %5, %0 op_sel:[0,0,0] op_sel_hi:[1,0,1] neg_lo:[0,1,0] neg_hi:[0,1,0]\n\t"
        "v_pk_fma_f32 %0, %3, %5, %0 op_sel:[1,1,0] op_sel_hi:[0,1,1] neg_lo:[0,1,0]\n\t"
        "v_pk_mul_f32 %1, %3, %4 op_sel:[0,0] op_sel_hi:[1,0]\n\t"
        "v_pk_fma_f32 %1, %3, %4, %1 op_sel:[1,1,0] op_sel_hi:[0,1,1] neg_lo:[0,1,0]\n\t"
        "v_pk_fma_f32 %1, %2, %5, %1 op_sel:[0,0,0] op_sel_hi:[1,0,1]\n\t"
        "v_pk_fma_f32 %1, %2, %5, %1 op_sel:[1,1,0] op_sel_hi:[0,1,1] neg_lo:[0,1,0]"
        : "=&v"(n0), "=&v"(n1)
        : "v"(a0), "v"(a1), "v"(ab), "v"(cd));
    a0 = n0; a1 = n1;
}

template<int P>
__device__ __forceinline__ void gate_on_bit(f32x2 a[16], f32x2 ab, f32x2 cd) {
    #pragma unroll
    for (int r = 0; r < 16; ++r)
        if (!(r & (1 << P)))
            app1p(ab, cd, a[r], a[r | (1 << P)]);
}

__global__ __launch_bounds__(NT, 2)   // VGPR budget 256, no spill
void tqhea_kernel(const float* __restrict__ x,     // (B, 24)
                  const float* __restrict__ wts,   // (6, 3, 12)
                  float* __restrict__ out)         // (B, 1)
{
    __shared__ f32x2  psi[NS];       // 32 KB, sig2-swizzled storage
    __shared__ float4 U[72];         // fused gates in ABCD form
    __shared__ float2 rxcs[12];      // (cos,sin) of first RX layer half-angles
    __shared__ float  redbuf[4];

    const int b = blockIdx.x;
    const int t = threadIdx.x;

    // ---- precompute fused U = RY(g)*RZ(b)*RY(a); block 3 also folds RX (mid encode)
    if (t < 72) {
        int ab = t / 12, w = t % 12;
        float a  = 0.5f * wts[(ab * 3 + 0) * 12 + w];
        float bb = 0.5f * wts[(ab * 3 + 1) * 12 + w];
        float g  = 0.5f * wts[(ab * 3 + 2) * 12 + w];
        float sa, ca, sb, cb, sg, cg;
        sincosf(a,  &sa, &ca);
        sincosf(bb, &sb, &cb);
        sincosf(g,  &sg, &cg);
        float A = cb * (ca * cg - sa * sg);
        float B = sb * (ca * cg + sa * sg);
        float C = cb * (sa * cg + ca * sg);
        float D = sb * (sa * cg - ca * sg);
        if (ab == 3) {                        // U' = U * RX(x[12+w])
            float th = 0.5f * x[b * 24 + 12 + w];
            float s, c; sincosf(th, &s, &c);
            float A2 = A*c + D*s, B2 = B*c - C*s, C2 = C*c + B*s, D2 = D*c - A*s;
            A = A2; B = B2; C = C2; D = D2;
        }
        U[t] = make_float4(A, B, C, D);
    }
    if (t < 12) {
        float th = 0.5f * x[b * 24 + t];
        float s, c; sincosf(th, &s, &c);
        rxcs[t] = make_float2(c, s);
    }
    __syncthreads();

    const int lo = t & 0xF, h = t >> 4;
    const int tb     = (t & 0xF0) | (lo ^ h);          // P0/init: addr = (r<<8)|(tb^r)
    const int baseP1 = (h << 8) | (lo ^ h);            // P1: addr = baseP1 ^ 17r
    const int baseP2 = (t << 4) | (lo ^ h);            // P2: addr = baseP2 ^ r
    const int Qt     = sig2(ring_pi_c(t << 4));        // ring scatter: addr = Qt ^ sig2(pi(r))
    const int Pt     = ring_pi_c(t << 4);              // for reduction diag

    // ---- init: |0..0> + first RX layer = product state (write-only pass)
    {
        float mlo = 1.f;
        #pragma unroll
        for (int bit = 0; bit < 8; ++bit)
            mlo *= ((t >> bit) & 1) ? rxcs[11 - bit].y : rxcs[11 - bit].x;
        int pct = __popc(t);
        #pragma unroll
        for (int r = 0; r < 16; ++r) {
            float mhi = 1.f;
            #pragma unroll
            for (int p = 0; p < 4; ++p)
                mhi *= ((r >> p) & 1) ? rxcs[3 - p].y : rxcs[3 - p].x;
            float mag = mhi * mlo;
            int pc = (pct + __popc(r)) & 3;            // (-i)^popcount phase
            f32x2 v;
            v.x = (pc == 0) ? mag : ((pc == 2) ? -mag : 0.f);
            v.y = (pc == 1) ? -mag : ((pc == 3) ? mag : 0.f);
            psi[(r << 8) | (tb ^ r)] = v;
        }
    }
    __syncthreads();

    float acc = 0.f;

    // ---- 6 ansatz layers; ring folded into P2 scatter-write (layers 0..4),
    //      last layer's ring + P2 fold straight into the reduction
    #pragma unroll 1
    for (int l = 0; l < 6; ++l) {
        f32x2 a[16];
        f32x2 gab, gcd;
        // P0: wires 0..3 (k bits 11..8 register-local)
        #pragma unroll
        for (int r = 0; r < 16; ++r) a[r] = psi[(r << 8) | (tb ^ r)];
        { float4 g = U[l*12+0]; gab = f32x2{g.x,g.y}; gcd = f32x2{g.z,g.w}; gate_on_bit<3>(a, gab, gcd); }
        { float4 g = U[l*12+1]; gab = f32x2{g.x,g.y}; gcd = f32x2{g.z,g.w}; gate_on_bit<2>(a, gab, gcd); }
        { float4 g = U[l*12+2]; gab = f32x2{g.x,g.y}; gcd = f32x2{g.z,g.w}; gate_on_bit<1>(a, gab, gcd); }
        { float4 g = U[l*12+3]; gab = f32x2{g.x,g.y}; gcd = f32x2{g.z,g.w}; gate_on_bit<0>(a, gab, gcd); }
        #pragma unroll
        for (int r = 0; r < 16; ++r) psi[(r << 8) | (tb ^ r)] = a[r];
        __syncthreads();

        // P1: wires 4..7 (k bits 7..4 register-local)
        #pragma unroll
        for (int r = 0; r < 16; ++r) a[r] = psi[baseP1 ^ (17 * r)];
        { float4 g = U[l*12+4]; gab = f32x2{g.x,g.y}; gcd = f32x2{g.z,g.w}; gate_on_bit<3>(a, gab, gcd); }
        { float4 g = U[l*12+5]; gab = f32x2{g.x,g.y}; gcd = f32x2{g.z,g.w}; gate_on_bit<2>(a, gab, gcd); }
        { float4 g = U[l*12+6]; gab = f32x2{g.x,g.y}; gcd = f32x2{g.z,g.w}; gate_on_bit<1>(a, gab, gcd); }
        { float4 g = U[l*12+7]; gab = f32x2{g.x,g.y}; gcd = f32x2{g.z,g.w}; gate_on_bit<0>(a, gab, gcd); }
        #pragma unroll
        for (int r = 0; r < 16; ++r) psi[baseP1 ^ (17 * r)] = a[r];
        __syncthreads();

        // P2: wires 8..11 (k bits 3..0 register-local); thread t, reg r hold k=(t<<4)|r
        #pragma unroll
        for (int r = 0; r < 16; ++r) a[r] = psi[baseP2 ^ r];
        if (l < 5) __syncthreads();        // all P2 reads complete before ring scatter
        { float4 g = U[l*12+8];  gab = f32x2{g.x,g.y}; gcd = f32x2{g.z,g.w}; gate_on_bit<3>(a, gab, gcd); }
        { float4 g = U[l*12+9];  gab = f32x2{g.x,g.y}; gcd = f32x2{g.z,g.w}; gate_on_bit<2>(a, gab, gcd); }
        { float4 g = U[l*12+10]; gab = f32x2{g.x,g.y}; gcd = f32x2{g.z,g.w}; gate_on_bit<1>(a, gab, gcd); }
        { float4 g = U[l*12+11]; gab = f32x2{g.x,g.y}; gcd = f32x2{g.z,g.w}; gate_on_bit<0>(a, gab, gcd); }
        if (l < 5) {
            // ring fold: psi_new[sig2(pi(k))] = a[r];  pi linear -> addr = Qt ^ const
            #pragma unroll
            for (int r = 0; r < 16; ++r)
                psi[Qt ^ sig2(ring_pi_c(r))] = a[r];
            __syncthreads();
        } else {
            // ---- <H>: final ring via pi; diag = 12 - 2*popc(pi(k))
            #pragma unroll
            for (int r = 0; r < 16; ++r) {
                float d = 12.0f - 2.0f * (float)__popc(Pt ^ ring_pi_c(r));
                acc += (a[r].x * a[r].x + a[r].y * a[r].y) * d;
            }
        }
    }

    #pragma unroll
    for (int off = 32; off > 0; off >>= 1)
        acc += __shfl_down(acc, off);
    int wid = t >> 6, lane = t & 63;
    if (lane == 0) redbuf[wid] = acc;
    __syncthreads();
    if (t == 0) out[b] = redbuf[0] + redbuf[1] + redbuf[2] + redbuf[3];
}

extern "C" void kernel_launch(void* const* d_in, const int* in_sizes, int n_in,
                              void* d_out, int out_size, void* d_ws, size_t ws_size,
                              hipStream_t stream) {
    const float* x   = (const float*)d_in[0];   // (B, 24) float32
    const float* wts = (const float*)d_in[1];   // (6, 3, 12) float32
    float* out = (float*)d_out;                 // (B, 1) float32
    int B = in_sizes[0] / 24;
    tqhea_kernel<<<dim3(B), dim3(NT), 0, stream>>>(x, wts, out);
}